// Round 5
// baseline (503.342 us; speedup 1.0000x reference)
//
#include <hip/hip_runtime.h>
#include <math.h>

// Problem constants (match reference)
constexpr int T_LEN = 15360;
constexpr int B_DIM = 64;
constexpr int C_DIM = 64;
constexpr int NTHR  = 256;
constexpr int KHALF = 12;                 // k=25 taps -> halo 12
constexpr int SEG    = 12;                // segments per row
constexpr int CH     = T_LEN / SEG;       // 1280 elems / segment
constexpr int EPT    = CH / NTHR;         // 5 elems / thread (odd -> benign LDS stride)
constexpr int F4SEG  = CH / 4;            // 320 float4 / segment

// ---- block-uniform affected flag via wave-0 ballot rank ----
__device__ __forceinline__ int compute_affected(const float* __restrict__ ch_u,
                                                const float* __restrict__ frac_u,
                                                const float* __restrict__ apply_u,
                                                int b, int c, int tid, int* s_aff)
{
    if (tid < 64) {
        const float myv = ch_u[(size_t)b * C_DIM + c];
        const float v   = ch_u[(size_t)b * C_DIM + tid];
        const bool pred = (v < myv) || (v == myv && tid < c);
        unsigned long long m = __ballot(pred);
        if (tid == 0) {
            int rank  = (int)__popcll(m);
            int n_aff = (int)floorf(((float)C_DIM * frac_u[b]) * 0.5f);
            if (n_aff < 1) n_aff = 1;
            *s_aff = (apply_u[b] <= 0.4f && rank < n_aff) ? 1 : 0;
        }
    }
    __syncthreads();
    return *s_aff;
}

struct BurstParams {
    float sf, endf, ef, inv_denom, head_end, tail_beg;
};

__device__ __forceinline__ BurstParams burst_params(const float* __restrict__ burst_u,
                                                    const float* __restrict__ start_u,
                                                    int b)
{
    const float bu   = burst_u[b];
    const float bfr  = 0.1f + bu * 0.4f;
    const int   blen = (int)floorf((float)T_LEN * bfr);
    int tmb = T_LEN - blen; if (tmb < 1) tmb = 1;
    const int   start = (int)floorf(start_u[b] * (float)tmb);
    const int   elen  = min(25, blen / 4);
    BurstParams p;
    p.sf   = (float)start;
    p.endf = p.sf + (float)blen;
    p.ef   = (float)elen;
    const float denom = fmaxf(p.ef - 1.0f, 1.0f);
    p.inv_denom = 1.0f / denom;
    p.head_end  = p.sf + p.ef;
    p.tail_beg  = p.endf - p.ef;
    return p;
}

// stage noise segment + halos into s_buf (interior at [KHALF, KHALF+CH))
__device__ __forceinline__ void stage_noise(const float* __restrict__ nrow, int g0,
                                            float* s_buf, int tid)
{
    const float4* nsrc = (const float4*)(nrow + g0);
    float4* sb4 = (float4*)(s_buf + KHALF);   // 48B offset -> 16B aligned
    #pragma unroll
    for (int it = 0; it < 2; ++it) {
        int q = tid + it * NTHR;
        if (q < F4SEG) sb4[q] = nsrc[q];
    }
    if (tid < KHALF) {
        int gl = g0 - KHALF + tid;
        s_buf[tid] = (gl >= 0) ? nrow[gl] : 0.f;
        int gr = g0 + CH + tid;
        s_buf[KHALF + CH + tid] = (gr < T_LEN) ? nrow[gr] : 0.f;
    }
}

// sliding 25-tap window over staged chunk; emits e[EPT] (emg_b values)
__device__ __forceinline__ void compute_emgb(const float* s_buf, int g0, int tid,
                                             const BurstParams& p, float* e)
{
    const float inv_k = 1.0f / 25.0f;
    const int l0 = KHALF + tid * EPT;
    float w = 0.f;
    #pragma unroll
    for (int d = -KHALF; d <= KHALF; ++d) w += s_buf[l0 + d];
    #pragma unroll
    for (int j = 0; j < EPT; ++j) {
        const float nv  = s_buf[l0 + j];
        const float emg = nv - w * inv_k;
        const float tt  = (float)(g0 + tid * EPT + j);
        const bool  inb = (tt >= p.sf) && (tt < p.endf);
        float ramped;
        if (tt < p.head_end)       ramped = (tt - p.sf) * p.inv_denom;
        else if (tt >= p.tail_beg) ramped = (p.endf - 1.0f - tt) * p.inv_denom;
        else                       ramped = 1.0f;
        const float m  = inb ? ((p.ef > 1.0f) ? ramped : 1.0f) : 0.0f;
        e[j] = emg * m;
        if (j < EPT - 1)
            w += s_buf[l0 + j + KHALF + 1] - s_buf[l0 + j - KHALF];
    }
}

// ============  Fused kernel: copy + stats + last-block-of-row apply  ============
__global__ __launch_bounds__(NTHR, 6)
void emg_fused_kernel(const float* __restrict__ x,
                      const float* __restrict__ noise,
                      const float* __restrict__ apply_u,
                      const float* __restrict__ frac_u,
                      const float* __restrict__ ch_u,
                      const float* __restrict__ burst_u,
                      const float* __restrict__ start_u,
                      const float* __restrict__ snr_u,
                      int*   __restrict__ counters,   // [4096], zeroed per call
                      float* __restrict__ partials,   // [4096][SEG][2]
                      float* __restrict__ out)
{
    const int idx = blockIdx.x;            // contiguous: idx*5KB is the address
    const int row = idx / SEG;
    const int seg = idx - row * SEG;
    const int b   = row >> 6;
    const int c   = row & 63;
    const int tid = threadIdx.x;

    __shared__ int   s_flag;
    __shared__ float s_red[8];
    __shared__ __align__(16) float s_buf[CH + 2 * KHALF + 1];

    const int g0 = seg * CH;
    const float*  xrow = x   + (size_t)row * T_LEN;
    float*        orow = out + (size_t)row * T_LEN;
    const float4* x4   = (const float4*)(xrow + g0);

    if (!compute_affected(ch_u, frac_u, apply_u, b, c, tid, &s_flag)) {
        // unaffected: copy this segment out = x (coalesced float4)
        float4* o4 = (float4*)(orow + g0);
        #pragma unroll
        for (int it = 0; it < 2; ++it) {
            int q = tid + it * NTHR;
            if (q < F4SEG) o4[q] = x4[q];
        }
        return;
    }

    const BurstParams p = burst_params(burst_u, start_u, b);
    const float* nrow = noise + (size_t)row * T_LEN;

    // ---- stats for this segment ----
    float sumx2 = 0.f;
    #pragma unroll
    for (int it = 0; it < 2; ++it) {
        int q = tid + it * NTHR;
        if (q < F4SEG) {
            float4 xv = x4[q];
            sumx2 += xv.x * xv.x + xv.y * xv.y + xv.z * xv.z + xv.w * xv.w;
        }
    }

    stage_noise(nrow, g0, s_buf, tid);
    __syncthreads();

    float e[EPT];
    compute_emgb(s_buf, g0, tid, p, e);
    float sume2 = 0.f;
    #pragma unroll
    for (int j = 0; j < EPT; ++j) sume2 += e[j] * e[j];

    // block reduction
    float v1 = sumx2, v2 = sume2;
    #pragma unroll
    for (int off = 32; off > 0; off >>= 1) {
        v1 += __shfl_down(v1, off, 64);
        v2 += __shfl_down(v2, off, 64);
    }
    const int wave = tid >> 6;
    if ((tid & 63) == 0) { s_red[wave] = v1; s_red[wave + 4] = v2; }
    __syncthreads();

    if (tid == 0) {
        float sx = s_red[0] + s_red[1] + s_red[2] + s_red[3];
        float se = s_red[4] + s_red[5] + s_red[6] + s_red[7];
        float* wdst = partials + ((size_t)row * SEG + seg) * 2;
        wdst[0] = sx;
        wdst[1] = se;
        __threadfence();                       // release partials
        int old = atomicAdd(&counters[row], 1);
        s_flag = (old == SEG - 1) ? 1 : 0;     // am I the 12th finisher?
    }
    __syncthreads();
    if (!s_flag) return;

    // ---- winner: apply the whole row ----
    if (tid == 0) {
        __threadfence();                       // acquire partials
        const float* wrow = partials + (size_t)row * SEG * 2;
        float sx = 0.f, se = 0.f;
        #pragma unroll
        for (int s = 0; s < SEG; ++s) { sx += wrow[2 * s]; se += wrow[2 * s + 1]; }
        const float sig_p = sqrtf(sx / (float)T_LEN) + 1e-8f;
        const float noi_p = sqrtf(se / (float)T_LEN) + 1e-8f;
        const float snr   = 0.5f + snr_u[b] * 2.5f;
        s_red[0] = sig_p / (noi_p * snr);
    }
    __syncthreads();
    const float coef = s_red[0];

    for (int ck = 0; ck < SEG; ++ck) {
        const int cg0 = ck * CH;
        __syncthreads();                       // prior chunk reads done
        stage_noise(nrow, cg0, s_buf, tid);
        __syncthreads();

        float ec[EPT];
        compute_emgb(s_buf, cg0, tid, p, ec);
        __syncthreads();                       // window reads done -> overwrite ok

        const int l0 = KHALF + tid * EPT;
        #pragma unroll
        for (int j = 0; j < EPT; ++j) s_buf[l0 + j] = ec[j];
        __syncthreads();

        // coalesced float4 output: out = x + coef * emg_b
        const float4* sb4  = (const float4*)(s_buf + KHALF);
        const float4* xsrc = (const float4*)(xrow + cg0);
        float4*       odst = (float4*)(orow + cg0);
        #pragma unroll
        for (int it = 0; it < 2; ++it) {
            int q = tid + it * NTHR;
            if (q < F4SEG) {
                float4 ev = sb4[q];
                float4 xv = xsrc[q];
                float4 ov;
                ov.x = xv.x + coef * ev.x;
                ov.y = xv.y + coef * ev.y;
                ov.z = xv.z + coef * ev.z;
                ov.w = xv.w + coef * ev.w;
                odst[q] = ov;
            }
        }
    }
}

extern "C" void kernel_launch(void* const* d_in, const int* in_sizes, int n_in,
                              void* d_out, int out_size, void* d_ws, size_t ws_size,
                              hipStream_t stream) {
    const float* x       = (const float*)d_in[0];
    const float* noise   = (const float*)d_in[1];
    const float* apply_u = (const float*)d_in[2];
    const float* frac_u  = (const float*)d_in[3];
    const float* ch_u    = (const float*)d_in[4];
    const float* burst_u = (const float*)d_in[5];
    const float* start_u = (const float*)d_in[6];
    const float* snr_u   = (const float*)d_in[7];
    float* out = (float*)d_out;

    // ws layout: [0,16KB) row counters (int), [16KB, 16KB+384KB) partials
    int*   counters = (int*)d_ws;
    float* partials = (float*)((char*)d_ws + 16 * 1024);

    hipMemsetAsync(counters, 0, B_DIM * C_DIM * sizeof(int), stream);

    dim3 grid(B_DIM * C_DIM * SEG);
    dim3 block(NTHR);
    emg_fused_kernel<<<grid, block, 0, stream>>>(
        x, noise, apply_u, frac_u, ch_u, burst_u, start_u, snr_u,
        counters, partials, out);
}

// Round 7
// 150.502 us; speedup vs baseline: 3.3444x; 3.3444x over previous
//
#include <hip/hip_runtime.h>
#include <math.h>

// Problem constants (match reference)
constexpr int T_LEN = 15360;
constexpr int B_DIM = 64;
constexpr int C_DIM = 64;
constexpr int NTHR  = 256;
constexpr int KHALF = 12;                 // k=25 taps -> halo 12
constexpr int SEG    = 12;                // segments per row
constexpr int CH     = T_LEN / SEG;       // 1280 elems / segment
constexpr int EPT    = CH / NTHR;         // 5 elems / thread (odd -> 2-way LDS alias, free)
constexpr int F4SEG  = CH / 4;            // 320 float4 / segment
constexpr int NROW   = B_DIM * C_DIM;     // 4096
constexpr int TSEG   = 4;                 // segments per A-block (20 KB contiguous)
constexpr int BPR    = SEG / TSEG;        // 3 A-blocks per row
constexpr int NABLK  = NROW * BPR;        // 12288
constexpr int NBBLK  = 2048;              // B-kernel fixed grid (8/CU)

typedef float f32x4 __attribute__((ext_vector_type(4)));

struct BurstParams {
    float sf, endf, ef, inv_denom, head_end, tail_beg;
};

__device__ __forceinline__ BurstParams burst_params(const float* __restrict__ burst_u,
                                                    const float* __restrict__ start_u,
                                                    int b)
{
    const float bu   = burst_u[b];
    const float bfr  = 0.1f + bu * 0.4f;
    const int   blen = (int)floorf((float)T_LEN * bfr);
    int tmb = T_LEN - blen; if (tmb < 1) tmb = 1;
    const int   start = (int)floorf(start_u[b] * (float)tmb);
    const int   elen  = min(25, blen / 4);
    BurstParams p;
    p.sf   = (float)start;
    p.endf = p.sf + (float)blen;
    p.ef   = (float)elen;
    const float denom = fmaxf(p.ef - 1.0f, 1.0f);
    p.inv_denom = 1.0f / denom;
    p.head_end  = p.sf + p.ef;
    p.tail_beg  = p.endf - p.ef;
    return p;
}

// stage noise segment + halos into s_buf (interior at [KHALF, KHALF+CH))
__device__ __forceinline__ void stage_noise(const float* __restrict__ nrow, int g0,
                                            float* s_buf, int tid)
{
    const f32x4* nsrc = (const f32x4*)(nrow + g0);
    f32x4* sb4 = (f32x4*)(s_buf + KHALF);   // 48B offset -> 16B aligned
    #pragma unroll
    for (int it = 0; it < 2; ++it) {
        int q = tid + it * NTHR;
        if (q < F4SEG) sb4[q] = nsrc[q];
    }
    if (tid < KHALF) {
        int gl = g0 - KHALF + tid;
        s_buf[tid] = (gl >= 0) ? nrow[gl] : 0.f;
        int gr = g0 + CH + tid;
        s_buf[KHALF + CH + tid] = (gr < T_LEN) ? nrow[gr] : 0.f;
    }
}

// sliding 25-tap window over staged chunk; emits e[EPT] (emg_b values)
__device__ __forceinline__ void compute_emgb(const float* s_buf, int g0, int tid,
                                             const BurstParams& p, float* e)
{
    const float inv_k = 1.0f / 25.0f;
    const int l0 = KHALF + tid * EPT;
    float w = 0.f;
    #pragma unroll
    for (int d = -KHALF; d <= KHALF; ++d) w += s_buf[l0 + d];
    #pragma unroll
    for (int j = 0; j < EPT; ++j) {
        const float nv  = s_buf[l0 + j];
        const float emg = nv - w * inv_k;
        const float tt  = (float)(g0 + tid * EPT + j);
        const bool  inb = (tt >= p.sf) && (tt < p.endf);
        float ramped;
        if (tt < p.head_end)       ramped = (tt - p.sf) * p.inv_denom;
        else if (tt >= p.tail_beg) ramped = (p.endf - 1.0f - tt) * p.inv_denom;
        else                       ramped = 1.0f;
        const float m  = inb ? ((p.ef > 1.0f) ? ramped : 1.0f) : 0.0f;
        e[j] = emg * m;
        if (j < EPT - 1)
            w += s_buf[l0 + j + KHALF + 1] - s_buf[l0 + j - KHALF];
    }
}

// ====  Kernel A: contiguous bulk copy (unaffected) + stats + list push  ====
__global__ __launch_bounds__(NTHR, 8)
void emg_bulk_stats_kernel(const float* __restrict__ x,
                           const float* __restrict__ noise,
                           const float* __restrict__ apply_u,
                           const float* __restrict__ frac_u,
                           const float* __restrict__ ch_u,
                           const float* __restrict__ burst_u,
                           const float* __restrict__ start_u,
                           int*   __restrict__ count,      // [1], zeroed per call
                           int*   __restrict__ list,       // [NABLK]
                           float* __restrict__ partials,   // [NABLK][2]
                           float* __restrict__ out)
{
    const int idx = blockIdx.x;            // contiguous: block owns 20KB span
    const int row = idx / BPR;
    const int bir = idx - row * BPR;
    const int b   = row >> 6;
    const int c   = row & 63;
    const int tid = threadIdx.x;
    const int g0  = bir * TSEG * CH;

    __shared__ int   s_aff;
    __shared__ float s_red[8];
    __shared__ __align__(16) float s_buf[CH + 2 * KHALF + 1];

    // affected predicate via wave-0 ballot rank
    if (tid < 64) {
        const float myv = ch_u[(size_t)b * C_DIM + c];
        const float v   = ch_u[(size_t)b * C_DIM + tid];
        const bool pred = (v < myv) || (v == myv && tid < c);
        unsigned long long m = __ballot(pred);
        if (tid == 0) {
            int rank  = (int)__popcll(m);
            int n_aff = (int)floorf(((float)C_DIM * frac_u[b]) * 0.5f);
            if (n_aff < 1) n_aff = 1;
            int aff = (apply_u[b] <= 0.4f && rank < n_aff) ? 1 : 0;
            s_aff = aff;
            if (aff) {
                int slot = atomicAdd(count, 1);
                list[slot] = idx;
            }
        }
    }
    __syncthreads();

    const float* xrow = x   + (size_t)row * T_LEN;
    float*       orow = out + (size_t)row * T_LEN;

    if (!s_aff) {
        // streaming 20KB copy: 1280 float4, 5/thread, nontemporal both sides
        const f32x4* xs = (const f32x4*)(xrow + g0);
        f32x4*       od = (f32x4*)(orow + g0);
        #pragma unroll
        for (int it = 0; it < TSEG * F4SEG / NTHR; ++it) {   // 5
            int q = tid + it * NTHR;
            f32x4 v = __builtin_nontemporal_load(&xs[q]);
            __builtin_nontemporal_store(v, &od[q]);
        }
        return;
    }

    // ---- affected: stats over 4 segments ----
    const BurstParams p = burst_params(burst_u, start_u, b);
    const float* nrow = noise + (size_t)row * T_LEN;

    float sumx2 = 0.f, sume2 = 0.f;
    for (int s = 0; s < TSEG; ++s) {
        const int sg0 = g0 + s * CH;
        const f32x4* x4 = (const f32x4*)(xrow + sg0);
        #pragma unroll
        for (int it = 0; it < 2; ++it) {
            int q = tid + it * NTHR;
            if (q < F4SEG) {
                f32x4 xv = x4[q];
                sumx2 += xv.x * xv.x + xv.y * xv.y + xv.z * xv.z + xv.w * xv.w;
            }
        }
        __syncthreads();   // prior seg's s_buf reads done
        stage_noise(nrow, sg0, s_buf, tid);
        __syncthreads();
        float e[EPT];
        compute_emgb(s_buf, sg0, tid, p, e);
        #pragma unroll
        for (int j = 0; j < EPT; ++j) sume2 += e[j] * e[j];
    }

    // block reduction
    float v1 = sumx2, v2 = sume2;
    #pragma unroll
    for (int off = 32; off > 0; off >>= 1) {
        v1 += __shfl_down(v1, off, 64);
        v2 += __shfl_down(v2, off, 64);
    }
    const int wave = tid >> 6;
    if ((tid & 63) == 0) { s_red[wave] = v1; s_red[wave + 4] = v2; }
    __syncthreads();
    if (tid == 0) {
        partials[(size_t)idx * 2]     = s_red[0] + s_red[1] + s_red[2] + s_red[3];
        partials[(size_t)idx * 2 + 1] = s_red[4] + s_red[5] + s_red[6] + s_red[7];
    }
}

// ====  Kernel B: apply over compacted affected list only  ====
__global__ __launch_bounds__(NTHR, 8)
void emg_apply_kernel(const float* __restrict__ x,
                      const float* __restrict__ noise,
                      const float* __restrict__ burst_u,
                      const float* __restrict__ start_u,
                      const float* __restrict__ snr_u,
                      const int*   __restrict__ count,
                      const int*   __restrict__ list,
                      const float* __restrict__ partials,
                      float* __restrict__ out)
{
    const int tid = threadIdx.x;
    __shared__ __align__(16) float s_buf[CH + 2 * KHALF + 1];

    const int n = count[0];
    for (int e = blockIdx.x; e < n; e += NBBLK) {
        const int idx = list[e];
        const int row = idx / BPR;
        const int bir = idx - row * BPR;
        const int b   = row >> 6;
        const int g0  = bir * TSEG * CH;

        // row sums from the 3 per-block partials (L2-hot)
        const float* pr = partials + (size_t)row * BPR * 2;
        const float sx = pr[0] + pr[2] + pr[4];
        const float se = pr[1] + pr[3] + pr[5];
        const float sig_p = sqrtf(sx / (float)T_LEN) + 1e-8f;
        const float noi_p = sqrtf(se / (float)T_LEN) + 1e-8f;
        const float snr   = 0.5f + snr_u[b] * 2.5f;
        const float coef  = sig_p / (noi_p * snr);

        const BurstParams p = burst_params(burst_u, start_u, b);
        const float* xrow = x     + (size_t)row * T_LEN;
        const float* nrow = noise + (size_t)row * T_LEN;
        float*       orow = out   + (size_t)row * T_LEN;

        for (int s = 0; s < TSEG; ++s) {
            const int sg0 = g0 + s * CH;
            __syncthreads();   // prior seg/entry s_buf reads done
            stage_noise(nrow, sg0, s_buf, tid);
            __syncthreads();

            float ev[EPT];
            compute_emgb(s_buf, sg0, tid, p, ev);
            __syncthreads();   // window reads done -> safe to overwrite interior

            const int l0 = KHALF + tid * EPT;
            #pragma unroll
            for (int j = 0; j < EPT; ++j) s_buf[l0 + j] = ev[j];
            __syncthreads();

            // coalesced float4 output: out = x + coef * emg_b
            const f32x4* sb4  = (const f32x4*)(s_buf + KHALF);
            const f32x4* xsrc = (const f32x4*)(xrow + sg0);
            f32x4*       odst = (f32x4*)(orow + sg0);
            #pragma unroll
            for (int it = 0; it < 2; ++it) {
                int q = tid + it * NTHR;
                if (q < F4SEG) {
                    f32x4 evv = sb4[q];
                    f32x4 xv  = xsrc[q];
                    f32x4 ov;
                    ov.x = xv.x + coef * evv.x;
                    ov.y = xv.y + coef * evv.y;
                    ov.z = xv.z + coef * evv.z;
                    ov.w = xv.w + coef * evv.w;
                    odst[q] = ov;
                }
            }
        }
    }
}

extern "C" void kernel_launch(void* const* d_in, const int* in_sizes, int n_in,
                              void* d_out, int out_size, void* d_ws, size_t ws_size,
                              hipStream_t stream) {
    const float* x       = (const float*)d_in[0];
    const float* noise   = (const float*)d_in[1];
    const float* apply_u = (const float*)d_in[2];
    const float* frac_u  = (const float*)d_in[3];
    const float* ch_u    = (const float*)d_in[4];
    const float* burst_u = (const float*)d_in[5];
    const float* start_u = (const float*)d_in[6];
    const float* snr_u   = (const float*)d_in[7];
    float* out = (float*)d_out;

    // ws layout: [0,256) count; [256, 256+NABLK*8) partials; then list
    int*   count    = (int*)d_ws;
    float* partials = (float*)((char*)d_ws + 256);
    int*   list     = (int*)((char*)d_ws + 256 + NABLK * 2 * sizeof(float));

    hipMemsetAsync(count, 0, sizeof(int), stream);

    emg_bulk_stats_kernel<<<dim3(NABLK), dim3(NTHR), 0, stream>>>(
        x, noise, apply_u, frac_u, ch_u, burst_u, start_u,
        count, list, partials, out);
    emg_apply_kernel<<<dim3(NBBLK), dim3(NTHR), 0, stream>>>(
        x, noise, burst_u, start_u, snr_u, count, list, partials, out);
}